// Round 11
// baseline (381.434 us; speedup 1.0000x reference)
//
#include <hip/hip_runtime.h>
#include <cmath>

typedef unsigned short ushort_t;
typedef __attribute__((ext_vector_type(8))) short short8;
typedef __attribute__((ext_vector_type(4))) float floatx4;

// Problem constants
#define NH    12
#define T     1024
#define ROWS  4096      // B*T
#define NE    768
#define KPA   832       // bf16 K-pad for 769/780 (multiple of 64)
#define KPB   3136      // bf16 K-pad for 3076 (multiple of 64)
#define NEXP  3200      // padded expand N (3075 -> 25*128)
#define HEXP  3075
#define NSPLIT 3        // attention split-S factor

// ---------------- helpers ----------------
__device__ __forceinline__ ushort_t f2bf(float f) {
  union { float f; unsigned u; } v; v.f = f;
  unsigned r = v.u + 0x7fffu + ((v.u >> 16) & 1u);
  return (ushort_t)(r >> 16);
}
__device__ __forceinline__ ushort_t f2bf_trunc(float f) {
  union { float f; unsigned u; } v; v.f = f;
  return (ushort_t)(v.u >> 16);
}
__device__ __forceinline__ float bf2f(ushort_t b) {
  union { unsigned u; float f; } v; v.u = ((unsigned)b) << 16;
  return v.f;
}
__device__ __forceinline__ float blk_reduce_sum(float v, float* sm) {
  #pragma unroll
  for (int o = 32; o > 0; o >>= 1) v += __shfl_xor(v, o, 64);
  int lane = threadIdx.x & 63, w = threadIdx.x >> 6;
  __syncthreads();
  if (lane == 0) sm[w] = v;
  __syncthreads();
  return sm[0] + sm[1] + sm[2] + sm[3];
}
__device__ __forceinline__ float red16_sum(float v) {
  #pragma unroll
  for (int o = 1; o < 16; o <<= 1) v += __shfl_xor(v, o, 64);
  return v;
}

// ------ merged prep: 4 weight pad-converts + aout pad zero + LN#1 -----------
#define NB_A 7488    // 2304*832/256
#define NB_B 2496    // 768*832/256
#define NB_C 10400   // 3200*832/256
#define NB_D 9408    // 768*3136/256
#define NB_E 16      // ROWS/256
__device__ __forceinline__ void cvt_elem(ushort_t* __restrict__ dst,
                                         const float* __restrict__ src,
                                         int idx, int srcRows, int srcK, int dstK) {
  int r = idx / dstK, c = idx - r * dstK;
  dst[idx] = (r < srcRows && c < srcK) ? f2bf(src[(size_t)r * srcK + c]) : (ushort_t)0;
}
__global__ __launch_bounds__(256) void prep_kernel(
    ushort_t* __restrict__ qkv_wb, const float* __restrict__ qkvw,
    ushort_t* __restrict__ proj_wb, const float* __restrict__ projw,
    ushort_t* __restrict__ exp_wb, const float* __restrict__ expw,
    ushort_t* __restrict__ shr_wb, const float* __restrict__ shrw,
    ushort_t* __restrict__ aout_bf,
    const float* __restrict__ xin, const float* __restrict__ g,
    const float* __restrict__ bb, const float* __restrict__ curv,
    ushort_t* __restrict__ lnp) {
  __shared__ float sm[4];
  int blk = blockIdx.x;
  int tid = threadIdx.x;
  if (blk < NB_A) {
    cvt_elem(qkv_wb, qkvw, blk * 256 + tid, 2304, 769, KPA);
  } else if (blk < NB_A + NB_B) {
    cvt_elem(proj_wb, projw, (blk - NB_A) * 256 + tid, 768, 780, KPA);
  } else if (blk < NB_A + NB_B + NB_C) {
    cvt_elem(exp_wb, expw, (blk - NB_A - NB_B) * 256 + tid, HEXP, 769, KPA);
  } else if (blk < NB_A + NB_B + NB_C + NB_D) {
    cvt_elem(shr_wb, shrw, (blk - NB_A - NB_B - NB_C) * 256 + tid, 768, 3076, KPB);
  } else if (blk < NB_A + NB_B + NB_C + NB_D + NB_E) {
    int r = (blk - NB_A - NB_B - NB_C - NB_D) * 256 + tid;
    ushort_t* p = aout_bf + (size_t)r * KPA + 780;
    #pragma unroll
    for (int j = 0; j < KPA - 780; ++j) p[j] = 0;
  } else {
    // layernorm + project row
    const int row = blk - (NB_A + NB_B + NB_C + NB_D + NB_E);
    const float* xr = xin + (size_t)row * NE;
    float xv[3];
    float s = 0.f, ss = 0.f;
    #pragma unroll
    for (int i = 0; i < 3; ++i) {
      xv[i] = xr[tid + 256 * i];
      s += xv[i]; ss += xv[i] * xv[i];
    }
    s = blk_reduce_sum(s, sm);
    ss = blk_reduce_sum(ss, sm);
    float mean = s * (1.f / 768.f);
    float var = ss * (1.f / 768.f) - mean * mean;
    float rstd = rsqrtf(var + 1e-5f);
    float yv[3]; float ys = 0.f;
    #pragma unroll
    for (int i = 0; i < 3; ++i) {
      int c = tid + 256 * i;
      yv[i] = (xv[i] - mean) * rstd * g[c] + bb[c];
      ys += yv[i] * yv[i];
    }
    ys = blk_reduce_sum(ys, sm);
    float tc = sqrtf(expf(curv[0]) + ys);
    ushort_t* orow = lnp + (size_t)row * KPA;
    #pragma unroll
    for (int i = 0; i < 3; ++i) orow[1 + tid + 256 * i] = f2bf(yv[i]);
    if (tid == 0) orow[0] = f2bf(tc);
    if (tid < KPA - 769) orow[769 + tid] = 0;
  }
}

// ---------------- bf16 MFMA NT GEMM, BK=64, swizzled LDS, optional split-K ---
// Round-8 proven structure. Single LDS buffer, 2 barriers/tile. The variants
// tried and REJECTED: 64KB dbuf (round-1: occupancy 5->2 blocks/CU, +4us),
// BK=32 dbuf (round-9: 2x barrier+stage overhead, 47->66us — per-tile compute
// [16 MFMA ~80cyc] can't hide ~400cyc load latency; hiding comes from
// cross-block TLP only), proj split-K=4 (round-10: +25MB partial traffic on a
// 13us dispatch, +6us total). Path past ~464 TF is the 8-phase 256^2 template.
// XCD-aware bijective block swizzle for L2 A-panel locality (round-2).
// Heavy epilogues (gelu) must NOT be fused (round-2: +27us).
__global__ __launch_bounds__(256) void gemm_bf16(
    const ushort_t* __restrict__ A, int lda,
    const ushort_t* __restrict__ W, int ldw,
    void* __restrict__ Cout, int ldc,
    int nkTot, int cpt,
    const float* __restrict__ bias, int biasN,
    const float* __restrict__ res, int ldres,
    int outMode, void* __restrict__ Cp) {
  __shared__ ushort_t As[128 * 64];
  __shared__ ushort_t Bs[128 * 64];
  const int tid = threadIdx.x;
  const int w = tid >> 6, lane = tid & 63;

  int bx = blockIdx.x, by = blockIdx.y;
  {
    const int gx = gridDim.x, gy = gridDim.y;
    const int nwg = gx * gy;
    if ((nwg & 7) == 0) {
      int lin = by * gx + bx;
      int swz = (lin & 7) * (nwg >> 3) + (lin >> 3);
      bx = swz % gx;
      by = swz / gx;
    }
  }
  const int rowBase = by << 7;
  const int colBase = bx << 7;
  const int wm = (w & 1) * 64, wn = (w >> 1) * 64;
  const int lm = lane & 15, quad = lane >> 4;
  const int p0 = quad ^ (lm & 7);   // fragment-read chunk position, s=0

  floatx4 acc[4][4];
  #pragma unroll
  for (int i = 0; i < 4; ++i)
    #pragma unroll
    for (int j = 0; j < 4; ++j) {
      floatx4 z = {0.f, 0.f, 0.f, 0.f};
      acc[i][j] = z;
    }

  const int kt0 = (int)blockIdx.z * cpt;
  const int kt1 = min(nkTot, kt0 + cpt);
  for (int kt = kt0; kt < kt1; ++kt) {
    __syncthreads();
    #pragma unroll
    for (int j = 0; j < 4; ++j) {
      int ci = j * 256 + tid;            // 16B chunk index 0..1023
      int r = ci >> 3;                   // row 0..127
      int g = (ci & 7) ^ (r & 7);        // global chunk stored at this position
      const ushort_t* ga = A + (size_t)(rowBase + r) * lda + kt * 64 + g * 8;
      const ushort_t* gb = W + (size_t)(colBase + r) * ldw + kt * 64 + g * 8;
      __builtin_amdgcn_global_load_lds(
          (const __attribute__((address_space(1))) void*)ga,
          (__attribute__((address_space(3))) void*)&As[(j * 256 + w * 64) * 8],
          16, 0, 0);
      __builtin_amdgcn_global_load_lds(
          (const __attribute__((address_space(1))) void*)gb,
          (__attribute__((address_space(3))) void*)&Bs[(j * 256 + w * 64) * 8],
          16, 0, 0);
    }
    __syncthreads();

    #pragma unroll
    for (int s = 0; s < 2; ++s) {
      const int ps = s ? (p0 ^ 4) : p0;
      short8 af[4], bfr[4];
      #pragma unroll
      for (int i = 0; i < 4; ++i) {
        af[i]  = *(const short8*)&As[(wm + i * 16 + lm) * 64 + ps * 8];
        bfr[i] = *(const short8*)&Bs[(wn + i * 16 + lm) * 64 + ps * 8];
      }
      #pragma unroll
      for (int i = 0; i < 4; ++i)
        #pragma unroll
        for (int jn = 0; jn < 4; ++jn)
          acc[i][jn] = __builtin_amdgcn_mfma_f32_16x16x32_bf16(
              af[i], bfr[jn], acc[i][jn], 0, 0, 0);
    }
  }

  if (gridDim.z > 1) {
    ushort_t* dst = (ushort_t*)Cp + (size_t)blockIdx.z * ROWS * ldc;
    #pragma unroll
    for (int i = 0; i < 4; ++i)
      #pragma unroll
      for (int jn = 0; jn < 4; ++jn) {
        const int col = colBase + wn + jn * 16 + lm;
        #pragma unroll
        for (int rg = 0; rg < 4; ++rg) {
          const int row = rowBase + wm + i * 16 + quad * 4 + rg;
          dst[(size_t)row * ldc + col] = f2bf(acc[i][jn][rg]);
        }
      }
  } else if (outMode == 1) {
    ushort_t* C = (ushort_t*)Cout;
    #pragma unroll
    for (int i = 0; i < 4; ++i)
      #pragma unroll
      for (int jn = 0; jn < 4; ++jn) {
        const int col = colBase + wn + jn * 16 + lm;
        const float bv = bias ? ((col < biasN) ? bias[col] : 0.f) : 0.f;
        #pragma unroll
        for (int rg = 0; rg < 4; ++rg) {
          const int row = rowBase + wm + i * 16 + quad * 4 + rg;
          C[(size_t)row * ldc + col] = f2bf(acc[i][jn][rg] + bv);
        }
      }
  } else {
    float* C = (float*)Cout;
    #pragma unroll
    for (int i = 0; i < 4; ++i)
      #pragma unroll
      for (int jn = 0; jn < 4; ++jn) {
        const int col = colBase + wn + jn * 16 + lm;
        const float bv = bias ? ((col < biasN) ? bias[col] : 0.f) : 0.f;
        #pragma unroll
        for (int rg = 0; rg < 4; ++rg) {
          const int row = rowBase + wm + i * 16 + quad * 4 + rg;
          float o = acc[i][jn][rg] + bv;
          if (res) o += res[(size_t)row * ldres + col];
          C[(size_t)row * ldc + col] = o;
        }
      }
  }
}

// ---------------- rotary + per-head hyperboloid project ----------------------
// input: 2 bf16 split-K partials of qkv (stride ROWS*2304) — reduce fused here
__global__ __launch_bounds__(256) void rope_project(
    const ushort_t* __restrict__ qkvp, const float* __restrict__ ac,
    ushort_t* __restrict__ qb, ushort_t* __restrict__ kb, ushort_t* __restrict__ vtb,
    float* __restrict__ q0, float* __restrict__ k0, float* __restrict__ v0) {
  int gid = blockIdx.x * 4 + (threadIdx.x >> 6);
  int lane = threadIdx.x & 63;
  int h = gid % NH;
  int bt = gid / NH;
  int t = bt & (T - 1);
  int b = bt >> 10;
  size_t base = (size_t)bt * 2304 + h * 64;
  const ushort_t* p1 = qkvp + (size_t)ROWS * 2304;
  float qv = bf2f(qkvp[base + lane])        + bf2f(p1[base + lane]);
  float kv = bf2f(qkvp[base + 768 + lane])  + bf2f(p1[base + 768 + lane]);
  float vv = bf2f(qkvp[base + 1536 + lane]) + bf2f(p1[base + 1536 + lane]);
  int f = lane & 31;
  // 10000^(-f/32) = exp2(-f * log2(10000)/32)
  float ang = (float)t * __builtin_amdgcn_exp2f(-(float)f * 0.4152410118661534f);
  float sn, cs;
  sincosf(ang, &sn, &cs);
  float qp = __shfl(qv, lane ^ 32, 64);
  float kp = __shfl(kv, lane ^ 32, 64);
  float qr = (lane < 32) ? (qv * cs + qp * sn) : (-qp * sn + qv * cs);
  float kr = (lane < 32) ? (kv * cs + kp * sn) : (-kp * sn + kv * cs);
  float Kh = expf(ac[h]);
  float sq = qr * qr, sk = kr * kr, sv = vv * vv;
  #pragma unroll
  for (int o = 32; o > 0; o >>= 1) {
    sq += __shfl_xor(sq, o, 64);
    sk += __shfl_xor(sk, o, 64);
    sv += __shfl_xor(sv, o, 64);
  }
  size_t idx = ((size_t)(b * NH + h) * T + t);
  qb[idx * 64 + lane] = f2bf(qr);
  kb[idx * 64 + lane] = f2bf(kr);
  vtb[(size_t)(b * NH + h) * (64 * T) + (size_t)lane * T + t] = f2bf(vv);
  if (lane == 0) {
    q0[idx] = sqrtf(Kh + sq);
    k0[idx] = sqrtf(Kh + sk);
    v0[idx] = sqrtf(Kh + sv);
  }
}

// ---------------- MFMA flash Lorentz attention, split-S, no-max softmax ------
// Round-5 structure (proven 49us): QBLK=128, 8 waves, double-buffered K/V
// async prefetch via global_load_lds (round-6 A/B: direct global->VGPR K/V
// loads = +44us, exposed L2 latency; gload_lds prefetch + barrier wins).
// LDS 50KB: Q and Ps share a per-wave 2304B region. launch_bounds(512,4) —
// NO min-waves=6 (round-4: spill disaster). XCD-clustered bh remap —
// all 24 blocks of one head share lin%8 -> same XCD L2 -> K/V panel reuse.
__global__ __launch_bounds__(512, 4) void attn_kernel(
    const ushort_t* __restrict__ qb, const ushort_t* __restrict__ kb,
    const ushort_t* __restrict__ vtb,
    const float* __restrict__ q0, const float* __restrict__ k0,
    const float* __restrict__ v0,
    const float* __restrict__ ac,
    ushort_t* __restrict__ Opart, float* __restrict__ lpart,
    float* __restrict__ a0part) {
  __shared__ ushort_t QP[8 * 1152];   // per-wave region: Q 16x64 then Ps 16x72
  __shared__ ushort_t Ks[2][64 * 64];
  __shared__ ushort_t Vts[2][64 * 64];

  // XCD-clustered bijective remap: lin -> (xcd=lin&7, r=lin>>3);
  // bh = xcd + 8*(r/24)  (so bh%8 == lin%8 for every block of that head),
  // within-head: split fastest, heavy qtiles first.
  int sIdx, qtile, bh;
  {
    const int lin = ((int)blockIdx.z * (int)gridDim.y + (int)blockIdx.y) * (int)gridDim.x
                    + (int)blockIdx.x;            // 0..1151
    const int c = lin & 7;
    const int r = lin >> 3;                       // 0..143
    bh = c + 8 * (r / 24);                        // 0..47
    const int t24 = r % 24;
    sIdx = t24 % NSPLIT;
    qtile = (T / 128) - 1 - (t24 / NSPLIT);       // heavy first
  }
  const int h = bh % NH;
  const int qt0 = qtile * 128;
  const int tid = threadIdx.x;
  const int w = tid >> 6, lane = tid & 63;
  const int lm = lane & 15, quad = lane >> 4;
  const int wm = w * 16;
  const int sw = lm & 7;
  const int preg = w * 1152;          // this wave's QP region (ushort offset)

  const int n = 2 * qtile + 2;            // k-tiles up to & incl. diagonal
  const int kbeg = (n * sIdx) / NSPLIT;
  const int kend = (n * (sIdx + 1)) / NSPLIT;
  const size_t pb = (size_t)(sIdx * 48 + bh) * T;

  if (kbeg >= kend) {  // empty split — neutral partial
    #pragma unroll
    for (int r = 0; r < 4; ++r) {
      const int i = qt0 + wm + quad * 4 + r;
      ushort_t* orow = Opart + (pb + i) * 64;
      #pragma unroll
      for (int nt = 0; nt < 4; ++nt) orow[nt * 16 + lm] = 0;
      if (lm == 0) { lpart[pb + i] = 0.f; a0part[pb + i] = 0.f; }
    }
    return;
  }

  const float Kh = expf(ac[h]);
  const float sqrtK = sqrtf(Kh);
  const float invK = 1.0f / Kh;
  const float nsK = -sqrtK;
  const bool k1 = (Kh == 1.0f);

  // ---- prologue: Q tile (2 chunks/thread) + first K/V tile + scalars ----
  {
    const ushort_t* qtp = qb + ((size_t)bh * T + qt0) * 64;
    #pragma unroll
    for (int j = 0; j < 2; ++j) {
      int g = j * 8 + w;                 // 8-row group 0..15
      int ci = g * 64 + lane;            // 16B chunk index
      int r = ci >> 3;
      int clog = ((ci & 7) ^ (r & 7)) * 8;
      // group g -> region g>>1, half g&1 (rows stay contiguous within region)
      __builtin_amdgcn_global_load_lds(
          (const __attribute__((address_space(1))) void*)(qtp + r * 64 + clog),
          (__attribute__((address_space(3))) void*)&QP[(g >> 1) * 1152 + (g & 1) * 512],
          16, 0, 0);
    }
  }
  const ushort_t* kbase = kb + (size_t)bh * T * 64;
  const ushort_t* vbh = vtb + (size_t)bh * (64 * T);
  const float* k0row = k0 + (size_t)bh * T;
  const float* v0row = v0 + (size_t)bh * T;
  const int ldr = tid >> 3;                       // K/V tile row (1 chunk/thread)
  const int ldcs = ((tid & 7) ^ (ldr & 7)) * 8;   // swizzled column
  {
    const int j0 = kbeg * 64;
    __builtin_amdgcn_global_load_lds(
        (const __attribute__((address_space(1))) void*)(kbase + (size_t)(j0 + ldr) * 64 + ldcs),
        (__attribute__((address_space(3))) void*)&Ks[0][w * 512], 16, 0, 0);
    __builtin_amdgcn_global_load_lds(
        (const __attribute__((address_space(1))) void*)(vbh + (size_t)ldr * T + j0 + ldcs),
        (__attribute__((address_space(3))) void*)&Vts[0][w * 512], 16, 0, 0);
  }
  float k0n[4], v0n[4];
  #pragma unroll
  for (int jt = 0; jt < 4; ++jt) {
    k0n[jt] = k0row[kbeg * 64 + jt * 16 + lm];
    v0n[jt] = v0row[kbeg * 64 + jt * 16 + lm];
  }
  float q0rv[4];
  #pragma unroll
  for (int r = 0; r < 4; ++r)
    q0rv[r] = q0[(size_t)bh * T + qt0 + wm + quad * 4 + r];

  asm volatile("s_waitcnt vmcnt(0)" ::: "memory");
  __builtin_amdgcn_s_barrier();
  __builtin_amdgcn_sched_barrier(0);

  // hoisted loop-invariant Q fragments (pinned in VGPRs — the LDS they came
  // from is reused for Ps, so the compiler must never re-load them)
  short8 qf0 = *(const short8*)&QP[preg + lm * 64 + ((0 + quad) ^ sw) * 8];
  short8 qf1 = *(const short8*)&QP[preg + lm * 64 + ((4 + quad) ^ sw) * 8];
  asm volatile("" : "+v"(qf0), "+v"(qf1));

  float lsum[4], a0r[4];
  floatx4 oacc[4];
  #pragma unroll
  for (int r = 0; r < 4; ++r) { lsum[r] = 0.f; a0r[r] = 0.f; }
  #pragma unroll
  for (int nt = 0; nt < 4; ++nt) { floatx4 z = {0.f,0.f,0.f,0.f}; oacc[nt] = z; }

  int cur = 0;
  for (int kt = kbeg; kt < kend; ++kt) {
    const bool hasNext = (kt + 1 < kend);
    float k0i[4], v0v[4];
    #pragma unroll
    for (int jt = 0; jt < 4; ++jt) { k0i[jt] = k0n[jt] * invK; v0v[jt] = v0n[jt]; }

    if (hasNext) {  // issue next tile early: overlaps with this tile's compute
      const int j0n = (kt + 1) * 64;
      __builtin_amdgcn_global_load_lds(
          (const __attribute__((address_space(1))) void*)(kbase + (size_t)(j0n + ldr) * 64 + ldcs),
          (__attribute__((address_space(3))) void*)&Ks[cur ^ 1][w * 512], 16, 0, 0);
      __builtin_amdgcn_global_load_lds(
          (const __attribute__((address_space(1))) void*)(vbh + (size_t)ldr * T + j0n + ldcs),
          (__attribute__((address_space(3))) void*)&Vts[cur ^ 1][w * 512], 16, 0, 0);
      #pragma unroll
      for (int jt = 0; jt < 4; ++jt) {
        k0n[jt] = k0row[j0n + jt * 16 + lm];
        v0n[jt] = v0row[j0n + jt * 16 + lm];
      }
    }

    const int j0 = kt * 64;
    const ushort_t* Kc = Ks[cur];
    const ushort_t* Vc = Vts[cur];

    floatx4 sacc[4];
    __builtin_amdgcn_s_setprio(1);
    #pragma unroll
    for (int jt = 0; jt < 4; ++jt) {
      const int krow = jt * 16 + lm;
      short8 kf0 = *(const short8*)&Kc[krow * 64 + ((0 + quad) ^ sw) * 8];
      short8 kf1 = *(const short8*)&Kc[krow * 64 + ((4 + quad) ^ sw) * 8];
      floatx4 z = {0.f, 0.f, 0.f, 0.f};
      z = __builtin_amdgcn_mfma_f32_16x16x32_bf16(qf0, kf0, z, 0, 0, 0);
      z = __builtin_amdgcn_mfma_f32_16x16x32_bf16(qf1, kf1, z, 0, 0, 0);
      sacc[jt] = z;
    }
    __builtin_amdgcn_s_setprio(0);

    const bool maskT = (kt >= 2 * qtile);   // tile touches the diagonal
    if (k1) {
      #pragma unroll
      for (int r = 0; r < 4; ++r) {
        const int i = qt0 + wm + quad * 4 + r;
        float ls = 0.f, a0s = 0.f;
        #pragma unroll
        for (int jt = 0; jt < 4; ++jt) {
          float c = fmaf(-invK, sacc[jt][r], q0rv[r] * k0i[jt]);
          c = fmaxf(c, 1.000001f);
          float p = c - sqrtf(fmaf(c, c, -1.f));   // exp(-arccosh(c)), K=1
          if (maskT && (j0 + jt * 16 + lm > i)) p = 0.f;
          ushort_t pb2 = f2bf_trunc(p);
          QP[preg + (quad * 4 + r) * 72 + jt * 16 + lm] = pb2;
          float pf = bf2f(pb2);
          ls += pf;
          a0s = fmaf(pf, v0v[jt], a0s);
        }
        lsum[r] += ls;
        a0r[r] += a0s;
      }
    } else {
      #pragma unroll
      for (int r = 0; r < 4; ++r) {
        const int i = qt0 + wm + quad * 4 + r;
        float ls = 0.f, a0s = 0.f;
        #pragma unroll
        for (int jt = 0; jt < 4; ++jt) {
          float c = fmaf(-invK, sacc[jt][r], q0rv[r] * k0i[jt]);
          c = fmaxf(c, 1.000001f);
          float z = c + sqrtf(fmaf(c, c, -1.f));
          // p = (c+sqrt(c^2-1))^(-sqrtK); v_log_f32 computes log2
          float p = __builtin_amdgcn_exp2f(nsK * __builtin_amdgcn_logf(z));
          if (maskT && (j0 + jt * 16 + lm > i)) p = 0.f;
          ushort_t pb2 = f2bf_trunc(p);
          QP[preg + (quad * 4 + r) * 72 + jt * 16 + lm] = pb2;
          float pf = bf2f(pb2);
          ls += pf;
          a0s = fmaf(pf, v0v[jt], a0s);
        }
        lsum[r] += ls;
        a0r[r] += a0s;
      }
    }

    short8 pf0 = *(const short8*)&QP[preg + lm * 72 + quad * 8];
    short8 pf1 = *(const short8*)&QP[preg + lm * 72 + 32 + quad * 8];
    __builtin_amdgcn_s_setprio(1);
    #pragma unroll
    for (int nt = 0; nt < 4; ++nt) {
      const int vrow = nt * 16 + lm;
      short8 vf0 = *(const short8*)&Vc[vrow * 64 + ((0 + quad) ^ sw) * 8];
      short8 vf1 = *(const short8*)&Vc[vrow * 64 + ((4 + quad) ^ sw) * 8];
      oacc[nt] = __builtin_amdgcn_mfma_f32_16x16x32_bf16(pf0, vf0, oacc[nt], 0, 0, 0);
      oacc[nt] = __builtin_amdgcn_mfma_f32_16x16x32_bf16(pf1, vf1, oacc[nt], 0, 0, 0);
    }
    __builtin_amdgcn_s_setprio(0);

    if (hasNext) {
      asm volatile("s_waitcnt vmcnt(0)" ::: "memory");
      __builtin_amdgcn_s_barrier();
      __builtin_amdgcn_sched_barrier(0);
    }
    cur ^= 1;
  }

  #pragma unroll
  for (int r = 0; r < 4; ++r) {
    float lf = red16_sum(lsum[r]);
    float a0f = red16_sum(a0r[r]);
    const int i = qt0 + wm + quad * 4 + r;
    ushort_t* orow = Opart + (pb + i) * 64;
    #pragma unroll
    for (int nt = 0; nt < 4; ++nt) orow[nt * 16 + lm] = f2bf(oacc[nt][r]);
    if (lm == 0) { lpart[pb + i] = lf; a0part[pb + i] = a0f; }
  }
}

// ---------------- combine split-S partials (plain sums) + Lorentz epilogue ---
__global__ __launch_bounds__(256) void attn_combine(
    const ushort_t* __restrict__ Opart, const float* __restrict__ lpart,
    const float* __restrict__ a0part,
    const float* __restrict__ ac, ushort_t* __restrict__ aout) {
  const int widx = blockIdx.x * 4 + (threadIdx.x >> 6);
  const int lane = threadIdx.x & 63;
  const int bh = widx >> 10;
  const int t = widx & 1023;
  const int h = bh % NH, b = bh / NH;
  float L = 0.f, A0 = 0.f, O = 0.f;
  #pragma unroll
  for (int sp = 0; sp < NSPLIT; ++sp) {
    const size_t r = (size_t)(sp * 48 + bh) * T + t;
    L += lpart[r];
    A0 += a0part[r];
    O += bf2f(Opart[r * 64 + lane]);
  }
  const float invl = 1.f / L;
  float av = O * invl;
  float ssq = av * av;
  #pragma unroll
  for (int o = 32; o > 0; o >>= 1) ssq += __shfl_xor(ssq, o, 64);
  float a0n = A0 * invl;
  float nsq = fmaxf(a0n * a0n - ssq, 1e-6f);
  float Kh = expf(ac[h]);
  float scale = sqrtf(Kh) * rsqrtf(nsq);
  ushort_t* orow = aout + (size_t)(b * T + t) * KPA + h * 65;
  orow[1 + lane] = f2bf(av * scale);
  if (lane == 0) orow[0] = f2bf(a0n * scale);
}

// ------ exact gelu + project: 2 bf16 split-K partials + bias -> bf16 hp ------
// standalone on purpose: memory-bound stream hides the erf VALU cost;
// expand split-K reduce fused here. Loads VECTORIZED short8 (G13: hipcc never
// auto-vectorizes bf16 — scalar 2B loads cost ~2x on this 52MB stream).
// Padded cols 3075..3199 are exact zeros in the partials (zero-padded weight
// rows), so unguarded vector loads are safe; bias guarded; stores stay scalar
// (the +1 column offset misaligns them; writes are half the read traffic).
__global__ __launch_bounds__(256) void gelu_project(
    const ushort_t* __restrict__ hsrc, const float* __restrict__ bias,
    const float* __restrict__ curv, ushort_t* __restrict__ hp) {
  __shared__ float sm[4];
  const int row = blockIdx.x;
  const int tid = threadIdx.x;
  const ushort_t* hr0 = hsrc + (size_t)row * NEXP;
  const ushort_t* hr1 = hr0 + (size_t)ROWS * NEXP;
  float gv[2][8];
  float ss = 0.f;
  #pragma unroll
  for (int i = 0; i < 2; ++i) {
    const int ch = i * 256 + tid;          // 8-elem chunk 0..399
    if (ch < NEXP / 8) {
      const int c0 = ch * 8;
      short8 a = *(const short8*)&hr0[c0];
      short8 b = *(const short8*)&hr1[c0];
      #pragma unroll
      for (int j = 0; j < 8; ++j) {
        const int c = c0 + j;
        float xx = bf2f((ushort_t)a[j]) + bf2f((ushort_t)b[j])
                 + ((c < HEXP) ? bias[c] : 0.f);
        float gg = 0.5f * xx * (1.f + erff(xx * 0.70710678118654752f));
        gv[i][j] = gg; ss += gg * gg;
      }
    }
  }
  ss = blk_reduce_sum(ss, sm);
  float tc = sqrtf(expf(curv[0]) + ss);
  ushort_t* orow = hp + (size_t)row * KPB;
  #pragma unroll
  for (int i = 0; i < 2; ++i) {
    const int ch = i * 256 + tid;
    if (ch < NEXP / 8) {
      const int c0 = ch * 8;
      #pragma unroll
      for (int j = 0; j < 8; ++j) {
        const int c = c0 + j;
        if (c < HEXP) orow[1 + c] = f2bf(gv[i][j]);
      }
    }
  }
  if (tid == 0) orow[0] = f2bf(tc);
  if (tid < KPB - (HEXP + 1)) orow[HEXP + 1 + tid] = 0;
}

// ------- fused: bf16 split-K reduce + bias + residual -> x2, then LN+project -
__global__ __launch_bounds__(256) void reduce_ln_project(
    const ushort_t* __restrict__ Cp, int nsplit,
    const float* __restrict__ bias, const float* __restrict__ res,
    float* __restrict__ x2out,
    const float* __restrict__ g, const float* __restrict__ bb,
    const float* __restrict__ curv, ushort_t* __restrict__ lnp) {
  __shared__ float sm[4];
  const int row = blockIdx.x;
  const int tid = threadIdx.x;
  float xv[3];
  float s = 0.f, ss = 0.f;
  #pragma unroll
  for (int i = 0; i < 3; ++i) {
    const int c = tid + 256 * i;
    float v = bias[c] + res[(size_t)row * NE + c];
    for (int sp = 0; sp < nsplit; ++sp)
      v += bf2f(Cp[(size_t)sp * ROWS * NE + (size_t)row * NE + c]);
    x2out[(size_t)row * NE + c] = v;
    xv[i] = v;
    s += v; ss += v * v;
  }
  s = blk_reduce_sum(s, sm);
  ss = blk_reduce_sum(ss, sm);
  float mean = s * (1.f / 768.f);
  float var = ss * (1.f / 768.f) - mean * mean;
  float rstd = rsqrtf(var + 1e-5f);
  float yv[3]; float ys = 0.f;
  #pragma unroll
  for (int i = 0; i < 3; ++i) {
    int c = tid + 256 * i;
    yv[i] = (xv[i] - mean) * rstd * g[c] + bb[c];
    ys += yv[i] * yv[i];
  }
  ys = blk_reduce_sum(ys, sm);
  float tc = sqrtf(expf(curv[0]) + ys);
  ushort_t* orow = lnp + (size_t)row * KPA;
  #pragma unroll
  for (int i = 0; i < 3; ++i) orow[1 + tid + 256 * i] = f2bf(yv[i]);
  if (tid == 0) orow[0] = f2bf(tc);
  if (tid < KPA - 769) orow[769 + tid] = 0;
}

// ------- fused: bf16 split-K reduce + bias + residual + final project -> out -
__global__ __launch_bounds__(256) void reduce_final_project(
    const ushort_t* __restrict__ Cp, int nsplit,
    const float* __restrict__ bias, const float* __restrict__ res,
    const float* __restrict__ curv, float* __restrict__ out) {
  __shared__ float sm[4];
  const int row = blockIdx.x;
  const int tid = threadIdx.x;
  float v[3]; float ss = 0.f;
  #pragma unroll
  for (int i = 0; i < 3; ++i) {
    const int c = tid + 256 * i;
    float t = bias[c] + res[(size_t)row * NE + c];
    for (int sp = 0; sp < nsplit; ++sp)
      t += bf2f(Cp[(size_t)sp * ROWS * NE + (size_t)row * NE + c]);
    v[i] = t; ss += t * t;
  }
  ss = blk_reduce_sum(ss, sm);
  float tc = sqrtf(expf(curv[0]) + ss);
  float* o = out + (size_t)row * 769;
  #pragma unroll
  for (int i = 0; i < 3; ++i) o[1 + tid + 256 * i] = v[i];
  if (tid == 0) o[0] = tc;
}

// ---------------- launcher ----------------
extern "C" void kernel_launch(void* const* d_in, const int* in_sizes, int n_in,
                              void* d_out, int out_size, void* d_ws, size_t ws_size,
                              hipStream_t stream) {
  (void)in_sizes; (void)n_in; (void)out_size; (void)ws_size;
  const float* x     = (const float*)d_in[0];
  const float* bc    = (const float*)d_in[1];
  const float* mc    = (const float*)d_in[2];
  const float* ac    = (const float*)d_in[3];
  const float* qkvw  = (const float*)d_in[4];
  const float* projw = (const float*)d_in[5];
  const float* projb = (const float*)d_in[6];
  const float* expw  = (const float*)d_in[7];
  const float* expb  = (const float*)d_in[8];
  const float* shrw  = (const float*)d_in[9];
  const float* shrb  = (const float*)d_in[10];
  const float* lng   = (const float*)d_in[11];
  const float* lnb   = (const float*)d_in[12];
  float* out = (float*)d_out;

  // ---- workspace layout (~119.6 MB worst phase) ----
  float* x2 = (float*)d_ws;                                  // 4096*768 f32
  ushort_t* qkv_wb  = (ushort_t*)(x2 + (size_t)ROWS * NE);   // 2304*832 bf16
  ushort_t* proj_wb = qkv_wb + (size_t)2304 * KPA;           // 768*832
  ushort_t* exp_wb  = proj_wb + (size_t)768 * KPA;           // 3200*832
  ushort_t* shr_wb  = exp_wb + (size_t)NEXP * KPA;           // 768*3136
  ushort_t* lnp_bf  = shr_wb + (size_t)768 * KPB;            // 4096*832
  ushort_t* aout_bf = lnp_bf + (size_t)ROWS * KPA;           // 4096*832
  char* r2 = (char*)(aout_bf + (size_t)ROWS * KPA);
  // r2 union #1 (attn phase)
  ushort_t* qkvp = (ushort_t*)r2;                            // 2*ROWS*2304 bf16
  ushort_t* qbb = qkvp + (size_t)2 * ROWS * 2304;
  ushort_t* kbb = qbb + (size_t)48 * T * 64;
  ushort_t* vtb = kbb + (size_t)48 * T * 64;
  float* q0b = (float*)(vtb + (size_t)48 * T * 64);
  float* k0b = q0b + (size_t)48 * T;
  float* v0b = k0b + (size_t)48 * T;
  ushort_t* Opart = (ushort_t*)(v0b + (size_t)48 * T);       // NSPLIT*48*T*64 bf16
  float* lpart = (float*)(Opart + (size_t)NSPLIT * 48 * T * 64);
  float* a0part = lpart + (size_t)NSPLIT * 48 * T;
  // proj split-K partials (alias r2 front — qkvp dead after rope; 12.6MB
  // fits well inside the 37.7MB dead region, Opart far beyond)
  ushort_t* ppartP = (ushort_t*)r2;                          // 2*ROWS*768 bf16
  // r2 union #2 (mlp phase)
  ushort_t* hbbf = (ushort_t*)r2;                            // 2*ROWS*NEXP bf16
  ushort_t* hp_bf = hbbf + (size_t)2 * ROWS * NEXP;          // ROWS*KPB bf16
  // shrink partials alias r2 front (hbbf dead after gelu_project; 12.6<52MB)
  ushort_t* ppartS = (ushort_t*)r2;                          // 4*ROWS*768 bf16

  // 0. merged weight conversions + pad zero + block_norm #1
  prep_kernel<<<NB_A + NB_B + NB_C + NB_D + NB_E + ROWS, 256, 0, stream>>>(
      qkv_wb, qkvw, proj_wb, projw, exp_wb, expw, shr_wb, shrw, aout_bf,
      x, lng, lnb, bc, lnp_bf);
  // 2. qkv = ln1p @ qkv_w^T  — split-K=2 (grid-starved at z=1: 576 blocks)
  gemm_bf16<<<dim3(2304 / 128, ROWS / 128, 2), 256, 0, stream>>>(
      lnp_bf, KPA, qkv_wb, KPA, nullptr, 2304, KPA / 64, 7,
      nullptr, 0, nullptr, 0, 0, qkvp);
  // 3. rotary + per-head project (qkv 2-partial reduce fused) -> bf16
  rope_project<<<(ROWS * NH) / 4, 256, 0, stream>>>(qkvp, ac, qbb, kbb, vtb, q0b, k0b, v0b);
  // 4. split-S MFMA Lorentz flash attention (QBLK=128) -> bf16 partials
  attn_kernel<<<dim3(NSPLIT, T / 128, 48), 512, 0, stream>>>(
      qbb, kbb, vtb, q0b, k0b, v0b, ac, Opart, lpart, a0part);
  attn_combine<<<(48 * T) / 4, 256, 0, stream>>>(Opart, lpart, a0part, ac, aout_bf);
  // 5+6. attn proj split-K=2 (round-10: z=4 cost +25MB partial traffic, revert)
  gemm_bf16<<<dim3(768 / 128, ROWS / 128, 2), 256, 0, stream>>>(
      aout_bf, KPA, proj_wb, KPA, nullptr, NE, KPA / 64, 7,
      nullptr, 0, nullptr, 0, 0, ppartP);
  reduce_ln_project<<<ROWS, 256, 0, stream>>>(
      ppartP, 2, projb, x, x2, lng, lnb, bc, lnp_bf);
  // 7. mlp expand — split-K=2
  gemm_bf16<<<dim3(NEXP / 128, ROWS / 128, 2), 256, 0, stream>>>(
      lnp_bf, KPA, exp_wb, KPA, nullptr, NEXP, KPA / 64, 7,
      nullptr, 0, nullptr, 0, 0, hbbf);
  // 8. gelu + project (expand 2-partial reduce + bias fused, short8 loads)
  gelu_project<<<ROWS, 256, 0, stream>>>(hbbf, expb, mc, hp_bf);
  // 9+10. mlp shrink split-K=4 (bf16 partials), fused reduce+final project
  gemm_bf16<<<dim3(768 / 128, ROWS / 128, 4), 256, 0, stream>>>(
      hp_bf, KPB, shr_wb, KPB, nullptr, NE, KPB / 64, 13,
      nullptr, 0, nullptr, 0, 0, ppartS);
  reduce_final_project<<<ROWS, 256, 0, stream>>>(
      ppartS, 4, shrb, x2, bc, out);
}

// Round 12
// 357.913 us; speedup vs baseline: 1.0657x; 1.0657x over previous
//
#include <hip/hip_runtime.h>
#include <cmath>

typedef unsigned short ushort_t;
typedef __attribute__((ext_vector_type(8))) short short8;
typedef __attribute__((ext_vector_type(4))) float floatx4;

// Problem constants
#define NH    12
#define T     1024
#define ROWS  4096      // B*T
#define NE    768
#define KPA   832       // bf16 K-pad for 769/780 (multiple of 64)
#define KPB   3136      // bf16 K-pad for 3076 (multiple of 64)
#define NEXP  3200      // padded expand N (3075 -> 25*128)
#define HEXP  3075
#define NSPLIT 3        // attention split-S factor

// ---------------- helpers ----------------
__device__ __forceinline__ ushort_t f2bf(float f) {
  union { float f; unsigned u; } v; v.f = f;
  unsigned r = v.u + 0x7fffu + ((v.u >> 16) & 1u);
  return (ushort_t)(r >> 16);
}
__device__ __forceinline__ ushort_t f2bf_trunc(float f) {
  union { float f; unsigned u; } v; v.f = f;
  return (ushort_t)(v.u >> 16);
}
__device__ __forceinline__ float bf2f(ushort_t b) {
  union { unsigned u; float f; } v; v.u = ((unsigned)b) << 16;
  return v.f;
}
__device__ __forceinline__ float blk_reduce_sum(float v, float* sm) {
  #pragma unroll
  for (int o = 32; o > 0; o >>= 1) v += __shfl_xor(v, o, 64);
  int lane = threadIdx.x & 63, w = threadIdx.x >> 6;
  __syncthreads();
  if (lane == 0) sm[w] = v;
  __syncthreads();
  return sm[0] + sm[1] + sm[2] + sm[3];
}
__device__ __forceinline__ float red16_sum(float v) {
  #pragma unroll
  for (int o = 1; o < 16; o <<= 1) v += __shfl_xor(v, o, 64);
  return v;
}

// ------ merged prep: 4 weight pad-converts + aout pad zero + LN#1 -----------
#define NB_A 7488    // 2304*832/256
#define NB_B 2496    // 768*832/256
#define NB_C 10400   // 3200*832/256
#define NB_D 9408    // 768*3136/256
#define NB_E 16      // ROWS/256
__device__ __forceinline__ void cvt_elem(ushort_t* __restrict__ dst,
                                         const float* __restrict__ src,
                                         int idx, int srcRows, int srcK, int dstK) {
  int r = idx / dstK, c = idx - r * dstK;
  dst[idx] = (r < srcRows && c < srcK) ? f2bf(src[(size_t)r * srcK + c]) : (ushort_t)0;
}
__global__ __launch_bounds__(256) void prep_kernel(
    ushort_t* __restrict__ qkv_wb, const float* __restrict__ qkvw,
    ushort_t* __restrict__ proj_wb, const float* __restrict__ projw,
    ushort_t* __restrict__ exp_wb, const float* __restrict__ expw,
    ushort_t* __restrict__ shr_wb, const float* __restrict__ shrw,
    ushort_t* __restrict__ aout_bf,
    const float* __restrict__ xin, const float* __restrict__ g,
    const float* __restrict__ bb, const float* __restrict__ curv,
    ushort_t* __restrict__ lnp) {
  __shared__ float sm[4];
  int blk = blockIdx.x;
  int tid = threadIdx.x;
  if (blk < NB_A) {
    cvt_elem(qkv_wb, qkvw, blk * 256 + tid, 2304, 769, KPA);
  } else if (blk < NB_A + NB_B) {
    cvt_elem(proj_wb, projw, (blk - NB_A) * 256 + tid, 768, 780, KPA);
  } else if (blk < NB_A + NB_B + NB_C) {
    cvt_elem(exp_wb, expw, (blk - NB_A - NB_B) * 256 + tid, HEXP, 769, KPA);
  } else if (blk < NB_A + NB_B + NB_C + NB_D) {
    cvt_elem(shr_wb, shrw, (blk - NB_A - NB_B - NB_C) * 256 + tid, 768, 3076, KPB);
  } else if (blk < NB_A + NB_B + NB_C + NB_D + NB_E) {
    int r = (blk - NB_A - NB_B - NB_C - NB_D) * 256 + tid;
    ushort_t* p = aout_bf + (size_t)r * KPA + 780;
    #pragma unroll
    for (int j = 0; j < KPA - 780; ++j) p[j] = 0;
  } else {
    // layernorm + project row
    const int row = blk - (NB_A + NB_B + NB_C + NB_D + NB_E);
    const float* xr = xin + (size_t)row * NE;
    float xv[3];
    float s = 0.f, ss = 0.f;
    #pragma unroll
    for (int i = 0; i < 3; ++i) {
      xv[i] = xr[tid + 256 * i];
      s += xv[i]; ss += xv[i] * xv[i];
    }
    s = blk_reduce_sum(s, sm);
    ss = blk_reduce_sum(ss, sm);
    float mean = s * (1.f / 768.f);
    float var = ss * (1.f / 768.f) - mean * mean;
    float rstd = rsqrtf(var + 1e-5f);
    float yv[3]; float ys = 0.f;
    #pragma unroll
    for (int i = 0; i < 3; ++i) {
      int c = tid + 256 * i;
      yv[i] = (xv[i] - mean) * rstd * g[c] + bb[c];
      ys += yv[i] * yv[i];
    }
    ys = blk_reduce_sum(ys, sm);
    float tc = sqrtf(expf(curv[0]) + ys);
    ushort_t* orow = lnp + (size_t)row * KPA;
    #pragma unroll
    for (int i = 0; i < 3; ++i) orow[1 + tid + 256 * i] = f2bf(yv[i]);
    if (tid == 0) orow[0] = f2bf(tc);
    if (tid < KPA - 769) orow[769 + tid] = 0;
  }
}

// ---------------- bf16 MFMA NT GEMM, BK=64, swizzled LDS, optional split-K ---
// Round-8 proven structure. Single LDS buffer, 2 barriers/tile. Variants tried
// and REJECTED across this session: 64KB dbuf (r1: occupancy 5->2 blocks/CU),
// BK=32 dbuf (r9: 2x barrier+stage overhead, 47->66us), proj split-K=4 (r10:
// +25MB partial traffic on a 13us dispatch), gelu-fusion epilogue (r2: +27us
// serial VALU). Path past ~464 TF here is the 8-phase 256^2 template only.
// XCD-aware bijective block swizzle for L2 A-panel locality (r2: FETCH -33%).
__global__ __launch_bounds__(256) void gemm_bf16(
    const ushort_t* __restrict__ A, int lda,
    const ushort_t* __restrict__ W, int ldw,
    void* __restrict__ Cout, int ldc,
    int nkTot, int cpt,
    const float* __restrict__ bias, int biasN,
    const float* __restrict__ res, int ldres,
    int outMode, void* __restrict__ Cp) {
  __shared__ ushort_t As[128 * 64];
  __shared__ ushort_t Bs[128 * 64];
  const int tid = threadIdx.x;
  const int w = tid >> 6, lane = tid & 63;

  int bx = blockIdx.x, by = blockIdx.y;
  {
    const int gx = gridDim.x, gy = gridDim.y;
    const int nwg = gx * gy;
    if ((nwg & 7) == 0) {
      int lin = by * gx + bx;
      int swz = (lin & 7) * (nwg >> 3) + (lin >> 3);
      bx = swz % gx;
      by = swz / gx;
    }
  }
  const int rowBase = by << 7;
  const int colBase = bx << 7;
  const int wm = (w & 1) * 64, wn = (w >> 1) * 64;
  const int lm = lane & 15, quad = lane >> 4;
  const int p0 = quad ^ (lm & 7);   // fragment-read chunk position, s=0

  floatx4 acc[4][4];
  #pragma unroll
  for (int i = 0; i < 4; ++i)
    #pragma unroll
    for (int j = 0; j < 4; ++j) {
      floatx4 z = {0.f, 0.f, 0.f, 0.f};
      acc[i][j] = z;
    }

  const int kt0 = (int)blockIdx.z * cpt;
  const int kt1 = min(nkTot, kt0 + cpt);
  for (int kt = kt0; kt < kt1; ++kt) {
    __syncthreads();
    #pragma unroll
    for (int j = 0; j < 4; ++j) {
      int ci = j * 256 + tid;            // 16B chunk index 0..1023
      int r = ci >> 3;                   // row 0..127
      int g = (ci & 7) ^ (r & 7);        // global chunk stored at this position
      const ushort_t* ga = A + (size_t)(rowBase + r) * lda + kt * 64 + g * 8;
      const ushort_t* gb = W + (size_t)(colBase + r) * ldw + kt * 64 + g * 8;
      __builtin_amdgcn_global_load_lds(
          (const __attribute__((address_space(1))) void*)ga,
          (__attribute__((address_space(3))) void*)&As[(j * 256 + w * 64) * 8],
          16, 0, 0);
      __builtin_amdgcn_global_load_lds(
          (const __attribute__((address_space(1))) void*)gb,
          (__attribute__((address_space(3))) void*)&Bs[(j * 256 + w * 64) * 8],
          16, 0, 0);
    }
    __syncthreads();

    #pragma unroll
    for (int s = 0; s < 2; ++s) {
      const int ps = s ? (p0 ^ 4) : p0;
      short8 af[4], bfr[4];
      #pragma unroll
      for (int i = 0; i < 4; ++i) {
        af[i]  = *(const short8*)&As[(wm + i * 16 + lm) * 64 + ps * 8];
        bfr[i] = *(const short8*)&Bs[(wn + i * 16 + lm) * 64 + ps * 8];
      }
      #pragma unroll
      for (int i = 0; i < 4; ++i)
        #pragma unroll
        for (int jn = 0; jn < 4; ++jn)
          acc[i][jn] = __builtin_amdgcn_mfma_f32_16x16x32_bf16(
              af[i], bfr[jn], acc[i][jn], 0, 0, 0);
    }
  }

  if (gridDim.z > 1) {
    ushort_t* dst = (ushort_t*)Cp + (size_t)blockIdx.z * ROWS * ldc;
    #pragma unroll
    for (int i = 0; i < 4; ++i)
      #pragma unroll
      for (int jn = 0; jn < 4; ++jn) {
        const int col = colBase + wn + jn * 16 + lm;
        #pragma unroll
        for (int rg = 0; rg < 4; ++rg) {
          const int row = rowBase + wm + i * 16 + quad * 4 + rg;
          dst[(size_t)row * ldc + col] = f2bf(acc[i][jn][rg]);
        }
      }
  } else if (outMode == 1) {
    ushort_t* C = (ushort_t*)Cout;
    #pragma unroll
    for (int i = 0; i < 4; ++i)
      #pragma unroll
      for (int jn = 0; jn < 4; ++jn) {
        const int col = colBase + wn + jn * 16 + lm;
        const float bv = bias ? ((col < biasN) ? bias[col] : 0.f) : 0.f;
        #pragma unroll
        for (int rg = 0; rg < 4; ++rg) {
          const int row = rowBase + wm + i * 16 + quad * 4 + rg;
          C[(size_t)row * ldc + col] = f2bf(acc[i][jn][rg] + bv);
        }
      }
  } else {
    float* C = (float*)Cout;
    #pragma unroll
    for (int i = 0; i < 4; ++i)
      #pragma unroll
      for (int jn = 0; jn < 4; ++jn) {
        const int col = colBase + wn + jn * 16 + lm;
        const float bv = bias ? ((col < biasN) ? bias[col] : 0.f) : 0.f;
        #pragma unroll
        for (int rg = 0; rg < 4; ++rg) {
          const int row = rowBase + wm + i * 16 + quad * 4 + rg;
          float o = acc[i][jn][rg] + bv;
          if (res) o += res[(size_t)row * ldres + col];
          C[(size_t)row * ldc + col] = o;
        }
      }
  }
}

// ---------------- rotary + per-head hyperboloid project ----------------------
// input: 2 bf16 split-K partials of qkv (stride ROWS*2304) — reduce fused here
__global__ __launch_bounds__(256) void rope_project(
    const ushort_t* __restrict__ qkvp, const float* __restrict__ ac,
    ushort_t* __restrict__ qb, ushort_t* __restrict__ kb, ushort_t* __restrict__ vtb,
    float* __restrict__ q0, float* __restrict__ k0, float* __restrict__ v0) {
  int gid = blockIdx.x * 4 + (threadIdx.x >> 6);
  int lane = threadIdx.x & 63;
  int h = gid % NH;
  int bt = gid / NH;
  int t = bt & (T - 1);
  int b = bt >> 10;
  size_t base = (size_t)bt * 2304 + h * 64;
  const ushort_t* p1 = qkvp + (size_t)ROWS * 2304;
  float qv = bf2f(qkvp[base + lane])        + bf2f(p1[base + lane]);
  float kv = bf2f(qkvp[base + 768 + lane])  + bf2f(p1[base + 768 + lane]);
  float vv = bf2f(qkvp[base + 1536 + lane]) + bf2f(p1[base + 1536 + lane]);
  int f = lane & 31;
  // 10000^(-f/32) = exp2(-f * log2(10000)/32)
  float ang = (float)t * __builtin_amdgcn_exp2f(-(float)f * 0.4152410118661534f);
  float sn, cs;
  sincosf(ang, &sn, &cs);
  float qp = __shfl(qv, lane ^ 32, 64);
  float kp = __shfl(kv, lane ^ 32, 64);
  float qr = (lane < 32) ? (qv * cs + qp * sn) : (-qp * sn + qv * cs);
  float kr = (lane < 32) ? (kv * cs + kp * sn) : (-kp * sn + kv * cs);
  float Kh = expf(ac[h]);
  float sq = qr * qr, sk = kr * kr, sv = vv * vv;
  #pragma unroll
  for (int o = 32; o > 0; o >>= 1) {
    sq += __shfl_xor(sq, o, 64);
    sk += __shfl_xor(sk, o, 64);
    sv += __shfl_xor(sv, o, 64);
  }
  size_t idx = ((size_t)(b * NH + h) * T + t);
  qb[idx * 64 + lane] = f2bf(qr);
  kb[idx * 64 + lane] = f2bf(kr);
  vtb[(size_t)(b * NH + h) * (64 * T) + (size_t)lane * T + t] = f2bf(vv);
  if (lane == 0) {
    q0[idx] = sqrtf(Kh + sq);
    k0[idx] = sqrtf(Kh + sk);
    v0[idx] = sqrtf(Kh + sv);
  }
}

// ---------------- MFMA flash Lorentz attention, split-S, no-max softmax ------
// Round-5 structure (proven 49us): QBLK=128, 8 waves, double-buffered K/V
// async prefetch via global_load_lds (round-6 A/B: direct global->VGPR K/V
// loads = +44us, exposed L2 latency; gload_lds prefetch + barrier wins).
// LDS 50KB: Q and Ps share a per-wave 2304B region. launch_bounds(512,4) —
// NO min-waves=6 (round-4: spill disaster). XCD-clustered bh remap —
// all 24 blocks of one head share lin%8 -> same XCD L2 -> K/V panel reuse.
__global__ __launch_bounds__(512, 4) void attn_kernel(
    const ushort_t* __restrict__ qb, const ushort_t* __restrict__ kb,
    const ushort_t* __restrict__ vtb,
    const float* __restrict__ q0, const float* __restrict__ k0,
    const float* __restrict__ v0,
    const float* __restrict__ ac,
    ushort_t* __restrict__ Opart, float* __restrict__ lpart,
    float* __restrict__ a0part) {
  __shared__ ushort_t QP[8 * 1152];   // per-wave region: Q 16x64 then Ps 16x72
  __shared__ ushort_t Ks[2][64 * 64];
  __shared__ ushort_t Vts[2][64 * 64];

  // XCD-clustered bijective remap: lin -> (xcd=lin&7, r=lin>>3);
  // bh = xcd + 8*(r/24)  (so bh%8 == lin%8 for every block of that head),
  // within-head: split fastest, heavy qtiles first.
  int sIdx, qtile, bh;
  {
    const int lin = ((int)blockIdx.z * (int)gridDim.y + (int)blockIdx.y) * (int)gridDim.x
                    + (int)blockIdx.x;            // 0..1151
    const int c = lin & 7;
    const int r = lin >> 3;                       // 0..143
    bh = c + 8 * (r / 24);                        // 0..47
    const int t24 = r % 24;
    sIdx = t24 % NSPLIT;
    qtile = (T / 128) - 1 - (t24 / NSPLIT);       // heavy first
  }
  const int h = bh % NH;
  const int qt0 = qtile * 128;
  const int tid = threadIdx.x;
  const int w = tid >> 6, lane = tid & 63;
  const int lm = lane & 15, quad = lane >> 4;
  const int wm = w * 16;
  const int sw = lm & 7;
  const int preg = w * 1152;          // this wave's QP region (ushort offset)

  const int n = 2 * qtile + 2;            // k-tiles up to & incl. diagonal
  const int kbeg = (n * sIdx) / NSPLIT;
  const int kend = (n * (sIdx + 1)) / NSPLIT;
  const size_t pb = (size_t)(sIdx * 48 + bh) * T;

  if (kbeg >= kend) {  // empty split — neutral partial
    #pragma unroll
    for (int r = 0; r < 4; ++r) {
      const int i = qt0 + wm + quad * 4 + r;
      ushort_t* orow = Opart + (pb + i) * 64;
      #pragma unroll
      for (int nt = 0; nt < 4; ++nt) orow[nt * 16 + lm] = 0;
      if (lm == 0) { lpart[pb + i] = 0.f; a0part[pb + i] = 0.f; }
    }
    return;
  }

  const float Kh = expf(ac[h]);
  const float sqrtK = sqrtf(Kh);
  const float invK = 1.0f / Kh;
  const float nsK = -sqrtK;
  const bool k1 = (Kh == 1.0f);

  // ---- prologue: Q tile (2 chunks/thread) + first K/V tile + scalars ----
  {
    const ushort_t* qtp = qb + ((size_t)bh * T + qt0) * 64;
    #pragma unroll
    for (int j = 0; j < 2; ++j) {
      int g = j * 8 + w;                 // 8-row group 0..15
      int ci = g * 64 + lane;            // 16B chunk index
      int r = ci >> 3;
      int clog = ((ci & 7) ^ (r & 7)) * 8;
      // group g -> region g>>1, half g&1 (rows stay contiguous within region)
      __builtin_amdgcn_global_load_lds(
          (const __attribute__((address_space(1))) void*)(qtp + r * 64 + clog),
          (__attribute__((address_space(3))) void*)&QP[(g >> 1) * 1152 + (g & 1) * 512],
          16, 0, 0);
    }
  }
  const ushort_t* kbase = kb + (size_t)bh * T * 64;
  const ushort_t* vbh = vtb + (size_t)bh * (64 * T);
  const float* k0row = k0 + (size_t)bh * T;
  const float* v0row = v0 + (size_t)bh * T;
  const int ldr = tid >> 3;                       // K/V tile row (1 chunk/thread)
  const int ldcs = ((tid & 7) ^ (ldr & 7)) * 8;   // swizzled column
  {
    const int j0 = kbeg * 64;
    __builtin_amdgcn_global_load_lds(
        (const __attribute__((address_space(1))) void*)(kbase + (size_t)(j0 + ldr) * 64 + ldcs),
        (__attribute__((address_space(3))) void*)&Ks[0][w * 512], 16, 0, 0);
    __builtin_amdgcn_global_load_lds(
        (const __attribute__((address_space(1))) void*)(vbh + (size_t)ldr * T + j0 + ldcs),
        (__attribute__((address_space(3))) void*)&Vts[0][w * 512], 16, 0, 0);
  }
  float k0n[4], v0n[4];
  #pragma unroll
  for (int jt = 0; jt < 4; ++jt) {
    k0n[jt] = k0row[kbeg * 64 + jt * 16 + lm];
    v0n[jt] = v0row[kbeg * 64 + jt * 16 + lm];
  }
  float q0rv[4];
  #pragma unroll
  for (int r = 0; r < 4; ++r)
    q0rv[r] = q0[(size_t)bh * T + qt0 + wm + quad * 4 + r];

  asm volatile("s_waitcnt vmcnt(0)" ::: "memory");
  __builtin_amdgcn_s_barrier();
  __builtin_amdgcn_sched_barrier(0);

  // hoisted loop-invariant Q fragments (pinned in VGPRs — the LDS they came
  // from is reused for Ps, so the compiler must never re-load them)
  short8 qf0 = *(const short8*)&QP[preg + lm * 64 + ((0 + quad) ^ sw) * 8];
  short8 qf1 = *(const short8*)&QP[preg + lm * 64 + ((4 + quad) ^ sw) * 8];
  asm volatile("" : "+v"(qf0), "+v"(qf1));

  float lsum[4], a0r[4];
  floatx4 oacc[4];
  #pragma unroll
  for (int r = 0; r < 4; ++r) { lsum[r] = 0.f; a0r[r] = 0.f; }
  #pragma unroll
  for (int nt = 0; nt < 4; ++nt) { floatx4 z = {0.f,0.f,0.f,0.f}; oacc[nt] = z; }

  int cur = 0;
  for (int kt = kbeg; kt < kend; ++kt) {
    const bool hasNext = (kt + 1 < kend);
    float k0i[4], v0v[4];
    #pragma unroll
    for (int jt = 0; jt < 4; ++jt) { k0i[jt] = k0n[jt] * invK; v0v[jt] = v0n[jt]; }

    if (hasNext) {  // issue next tile early: overlaps with this tile's compute
      const int j0n = (kt + 1) * 64;
      __builtin_amdgcn_global_load_lds(
          (const __attribute__((address_space(1))) void*)(kbase + (size_t)(j0n + ldr) * 64 + ldcs),
          (__attribute__((address_space(3))) void*)&Ks[cur ^ 1][w * 512], 16, 0, 0);
      __builtin_amdgcn_global_load_lds(
          (const __attribute__((address_space(1))) void*)(vbh + (size_t)ldr * T + j0n + ldcs),
          (__attribute__((address_space(3))) void*)&Vts[cur ^ 1][w * 512], 16, 0, 0);
      #pragma unroll
      for (int jt = 0; jt < 4; ++jt) {
        k0n[jt] = k0row[j0n + jt * 16 + lm];
        v0n[jt] = v0row[j0n + jt * 16 + lm];
      }
    }

    const int j0 = kt * 64;
    const ushort_t* Kc = Ks[cur];
    const ushort_t* Vc = Vts[cur];

    floatx4 sacc[4];
    __builtin_amdgcn_s_setprio(1);
    #pragma unroll
    for (int jt = 0; jt < 4; ++jt) {
      const int krow = jt * 16 + lm;
      short8 kf0 = *(const short8*)&Kc[krow * 64 + ((0 + quad) ^ sw) * 8];
      short8 kf1 = *(const short8*)&Kc[krow * 64 + ((4 + quad) ^ sw) * 8];
      floatx4 z = {0.f, 0.f, 0.f, 0.f};
      z = __builtin_amdgcn_mfma_f32_16x16x32_bf16(qf0, kf0, z, 0, 0, 0);
      z = __builtin_amdgcn_mfma_f32_16x16x32_bf16(qf1, kf1, z, 0, 0, 0);
      sacc[jt] = z;
    }
    __builtin_amdgcn_s_setprio(0);

    const bool maskT = (kt >= 2 * qtile);   // tile touches the diagonal
    if (k1) {
      #pragma unroll
      for (int r = 0; r < 4; ++r) {
        const int i = qt0 + wm + quad * 4 + r;
        float ls = 0.f, a0s = 0.f;
        #pragma unroll
        for (int jt = 0; jt < 4; ++jt) {
          float c = fmaf(-invK, sacc[jt][r], q0rv[r] * k0i[jt]);
          c = fmaxf(c, 1.000001f);
          float p = c - sqrtf(fmaf(c, c, -1.f));   // exp(-arccosh(c)), K=1
          if (maskT && (j0 + jt * 16 + lm > i)) p = 0.f;
          ushort_t pb2 = f2bf_trunc(p);
          QP[preg + (quad * 4 + r) * 72 + jt * 16 + lm] = pb2;
          float pf = bf2f(pb2);
          ls += pf;
          a0s = fmaf(pf, v0v[jt], a0s);
        }
        lsum[r] += ls;
        a0r[r] += a0s;
      }
    } else {
      #pragma unroll
      for (int r = 0; r < 4; ++r) {
        const int i = qt0 + wm + quad * 4 + r;
        float ls = 0.f, a0s = 0.f;
        #pragma unroll
        for (int jt = 0; jt < 4; ++jt) {
          float c = fmaf(-invK, sacc[jt][r], q0rv[r] * k0i[jt]);
          c = fmaxf(c, 1.000001f);
          float z = c + sqrtf(fmaf(c, c, -1.f));
          // p = (c+sqrt(c^2-1))^(-sqrtK); v_log_f32 computes log2
          float p = __builtin_amdgcn_exp2f(nsK * __builtin_amdgcn_logf(z));
          if (maskT && (j0 + jt * 16 + lm > i)) p = 0.f;
          ushort_t pb2 = f2bf_trunc(p);
          QP[preg + (quad * 4 + r) * 72 + jt * 16 + lm] = pb2;
          float pf = bf2f(pb2);
          ls += pf;
          a0s = fmaf(pf, v0v[jt], a0s);
        }
        lsum[r] += ls;
        a0r[r] += a0s;
      }
    }

    short8 pf0 = *(const short8*)&QP[preg + lm * 72 + quad * 8];
    short8 pf1 = *(const short8*)&QP[preg + lm * 72 + 32 + quad * 8];
    __builtin_amdgcn_s_setprio(1);
    #pragma unroll
    for (int nt = 0; nt < 4; ++nt) {
      const int vrow = nt * 16 + lm;
      short8 vf0 = *(const short8*)&Vc[vrow * 64 + ((0 + quad) ^ sw) * 8];
      short8 vf1 = *(const short8*)&Vc[vrow * 64 + ((4 + quad) ^ sw) * 8];
      oacc[nt] = __builtin_amdgcn_mfma_f32_16x16x32_bf16(pf0, vf0, oacc[nt], 0, 0, 0);
      oacc[nt] = __builtin_amdgcn_mfma_f32_16x16x32_bf16(pf1, vf1, oacc[nt], 0, 0, 0);
    }
    __builtin_amdgcn_s_setprio(0);

    if (hasNext) {
      asm volatile("s_waitcnt vmcnt(0)" ::: "memory");
      __builtin_amdgcn_s_barrier();
      __builtin_amdgcn_sched_barrier(0);
    }
    cur ^= 1;
  }

  #pragma unroll
  for (int r = 0; r < 4; ++r) {
    float lf = red16_sum(lsum[r]);
    float a0f = red16_sum(a0r[r]);
    const int i = qt0 + wm + quad * 4 + r;
    ushort_t* orow = Opart + (pb + i) * 64;
    #pragma unroll
    for (int nt = 0; nt < 4; ++nt) orow[nt * 16 + lm] = f2bf(oacc[nt][r]);
    if (lm == 0) { lpart[pb + i] = lf; a0part[pb + i] = a0f; }
  }
}

// ---------------- combine split-S partials (plain sums) + Lorentz epilogue ---
__global__ __launch_bounds__(256) void attn_combine(
    const ushort_t* __restrict__ Opart, const float* __restrict__ lpart,
    const float* __restrict__ a0part,
    const float* __restrict__ ac, ushort_t* __restrict__ aout) {
  const int widx = blockIdx.x * 4 + (threadIdx.x >> 6);
  const int lane = threadIdx.x & 63;
  const int bh = widx >> 10;
  const int t = widx & 1023;
  const int h = bh % NH, b = bh / NH;
  float L = 0.f, A0 = 0.f, O = 0.f;
  #pragma unroll
  for (int sp = 0; sp < NSPLIT; ++sp) {
    const size_t r = (size_t)(sp * 48 + bh) * T + t;
    L += lpart[r];
    A0 += a0part[r];
    O += bf2f(Opart[r * 64 + lane]);
  }
  const float invl = 1.f / L;
  float av = O * invl;
  float ssq = av * av;
  #pragma unroll
  for (int o = 32; o > 0; o >>= 1) ssq += __shfl_xor(ssq, o, 64);
  float a0n = A0 * invl;
  float nsq = fmaxf(a0n * a0n - ssq, 1e-6f);
  float Kh = expf(ac[h]);
  float scale = sqrtf(Kh) * rsqrtf(nsq);
  ushort_t* orow = aout + (size_t)(b * T + t) * KPA + h * 65;
  orow[1 + lane] = f2bf(av * scale);
  if (lane == 0) orow[0] = f2bf(a0n * scale);
}

// ------ exact gelu + project: 2 bf16 split-K partials + bias -> bf16 hp ------
// standalone on purpose: memory-bound stream hides the erf VALU cost;
// expand split-K reduce fused here. SCALAR stride-256 access kept on purpose:
// round-11 A/B showed per-thread 8-seq-elem "vectorization" de-coalesces the
// STORES (2B/lane at 16B stride = 1/8 line utilization) and cost +21us. The
// stride-256 pattern is fully coalesced both directions (128B/wave/instr).
__global__ __launch_bounds__(256) void gelu_project(
    const ushort_t* __restrict__ hsrc, const float* __restrict__ bias,
    const float* __restrict__ curv, ushort_t* __restrict__ hp) {
  __shared__ float sm[4];
  const int row = blockIdx.x;
  const int tid = threadIdx.x;
  const ushort_t* hr0 = hsrc + (size_t)row * NEXP;
  const ushort_t* hr1 = hr0 + (size_t)ROWS * NEXP;
  float gv[13];
  float ss = 0.f;
  #pragma unroll
  for (int i = 0; i < 13; ++i) {
    int c = tid + 256 * i;
    float xx = (c < HEXP) ? (bf2f(hr0[c]) + bf2f(hr1[c]) + bias[c]) : 0.f;
    float gg = 0.5f * xx * (1.f + erff(xx * 0.70710678118654752f));
    gv[i] = gg; ss += gg * gg;
  }
  ss = blk_reduce_sum(ss, sm);
  float tc = sqrtf(expf(curv[0]) + ss);
  ushort_t* orow = hp + (size_t)row * KPB;
  #pragma unroll
  for (int i = 0; i < 13; ++i) {
    int c = tid + 256 * i;
    if (c < HEXP) orow[1 + c] = f2bf(gv[i]);
  }
  if (tid == 0) orow[0] = f2bf(tc);
  if (tid < KPB - (HEXP + 1)) orow[HEXP + 1 + tid] = 0;
}

// ------- fused: bf16 split-K reduce + bias + residual -> x2, then LN+project -
__global__ __launch_bounds__(256) void reduce_ln_project(
    const ushort_t* __restrict__ Cp, int nsplit,
    const float* __restrict__ bias, const float* __restrict__ res,
    float* __restrict__ x2out,
    const float* __restrict__ g, const float* __restrict__ bb,
    const float* __restrict__ curv, ushort_t* __restrict__ lnp) {
  __shared__ float sm[4];
  const int row = blockIdx.x;
  const int tid = threadIdx.x;
  float xv[3];
  float s = 0.f, ss = 0.f;
  #pragma unroll
  for (int i = 0; i < 3; ++i) {
    const int c = tid + 256 * i;
    float v = bias[c] + res[(size_t)row * NE + c];
    for (int sp = 0; sp < nsplit; ++sp)
      v += bf2f(Cp[(size_t)sp * ROWS * NE + (size_t)row * NE + c]);
    x2out[(size_t)row * NE + c] = v;
    xv[i] = v;
    s += v; ss += v * v;
  }
  s = blk_reduce_sum(s, sm);
  ss = blk_reduce_sum(ss, sm);
  float mean = s * (1.f / 768.f);
  float var = ss * (1.f / 768.f) - mean * mean;
  float rstd = rsqrtf(var + 1e-5f);
  float yv[3]; float ys = 0.f;
  #pragma unroll
  for (int i = 0; i < 3; ++i) {
    int c = tid + 256 * i;
    yv[i] = (xv[i] - mean) * rstd * g[c] + bb[c];
    ys += yv[i] * yv[i];
  }
  ys = blk_reduce_sum(ys, sm);
  float tc = sqrtf(expf(curv[0]) + ys);
  ushort_t* orow = lnp + (size_t)row * KPA;
  #pragma unroll
  for (int i = 0; i < 3; ++i) orow[1 + tid + 256 * i] = f2bf(yv[i]);
  if (tid == 0) orow[0] = f2bf(tc);
  if (tid < KPA - 769) orow[769 + tid] = 0;
}

// ------- fused: bf16 split-K reduce + bias + residual + final project -> out -
__global__ __launch_bounds__(256) void reduce_final_project(
    const ushort_t* __restrict__ Cp, int nsplit,
    const float* __restrict__ bias, const float* __restrict__ res,
    const float* __restrict__ curv, float* __restrict__ out) {
  __shared__ float sm[4];
  const int row = blockIdx.x;
  const int tid = threadIdx.x;
  float v[3]; float ss = 0.f;
  #pragma unroll
  for (int i = 0; i < 3; ++i) {
    const int c = tid + 256 * i;
    float t = bias[c] + res[(size_t)row * NE + c];
    for (int sp = 0; sp < nsplit; ++sp)
      t += bf2f(Cp[(size_t)sp * ROWS * NE + (size_t)row * NE + c]);
    v[i] = t; ss += t * t;
  }
  ss = blk_reduce_sum(ss, sm);
  float tc = sqrtf(expf(curv[0]) + ss);
  float* o = out + (size_t)row * 769;
  #pragma unroll
  for (int i = 0; i < 3; ++i) o[1 + tid + 256 * i] = v[i];
  if (tid == 0) o[0] = tc;
}

// ---------------- launcher ----------------
extern "C" void kernel_launch(void* const* d_in, const int* in_sizes, int n_in,
                              void* d_out, int out_size, void* d_ws, size_t ws_size,
                              hipStream_t stream) {
  (void)in_sizes; (void)n_in; (void)out_size; (void)ws_size;
  const float* x     = (const float*)d_in[0];
  const float* bc    = (const float*)d_in[1];
  const float* mc    = (const float*)d_in[2];
  const float* ac    = (const float*)d_in[3];
  const float* qkvw  = (const float*)d_in[4];
  const float* projw = (const float*)d_in[5];
  const float* projb = (const float*)d_in[6];
  const float* expw  = (const float*)d_in[7];
  const float* expb  = (const float*)d_in[8];
  const float* shrw  = (const float*)d_in[9];
  const float* shrb  = (const float*)d_in[10];
  const float* lng   = (const float*)d_in[11];
  const float* lnb   = (const float*)d_in[12];
  float* out = (float*)d_out;

  // ---- workspace layout (~119.6 MB worst phase) ----
  float* x2 = (float*)d_ws;                                  // 4096*768 f32
  ushort_t* qkv_wb  = (ushort_t*)(x2 + (size_t)ROWS * NE);   // 2304*832 bf16
  ushort_t* proj_wb = qkv_wb + (size_t)2304 * KPA;           // 768*832
  ushort_t* exp_wb  = proj_wb + (size_t)768 * KPA;           // 3200*832
  ushort_t* shr_wb  = exp_wb + (size_t)NEXP * KPA;           // 768*3136
  ushort_t* lnp_bf  = shr_wb + (size_t)768 * KPB;            // 4096*832
  ushort_t* aout_bf = lnp_bf + (size_t)ROWS * KPA;           // 4096*832
  char* r2 = (char*)(aout_bf + (size_t)ROWS * KPA);
  // r2 union #1 (attn phase)
  ushort_t* qkvp = (ushort_t*)r2;                            // 2*ROWS*2304 bf16
  ushort_t* qbb = qkvp + (size_t)2 * ROWS * 2304;
  ushort_t* kbb = qbb + (size_t)48 * T * 64;
  ushort_t* vtb = kbb + (size_t)48 * T * 64;
  float* q0b = (float*)(vtb + (size_t)48 * T * 64);
  float* k0b = q0b + (size_t)48 * T;
  float* v0b = k0b + (size_t)48 * T;
  ushort_t* Opart = (ushort_t*)(v0b + (size_t)48 * T);       // NSPLIT*48*T*64 bf16
  float* lpart = (float*)(Opart + (size_t)NSPLIT * 48 * T * 64);
  float* a0part = lpart + (size_t)NSPLIT * 48 * T;
  // proj split-K partials (alias r2 front — qkvp dead after rope; 12.6MB
  // fits well inside the 37.7MB dead region, Opart far beyond)
  ushort_t* ppartP = (ushort_t*)r2;                          // 2*ROWS*768 bf16
  // r2 union #2 (mlp phase)
  ushort_t* hbbf = (ushort_t*)r2;                            // 2*ROWS*NEXP bf16
  ushort_t* hp_bf = hbbf + (size_t)2 * ROWS * NEXP;          // ROWS*KPB bf16
  // shrink partials alias r2 front (hbbf dead after gelu_project; 12.6<52MB)
  ushort_t* ppartS = (ushort_t*)r2;                          // 4*ROWS*768 bf16

  // 0. merged weight conversions + pad zero + block_norm #1
  prep_kernel<<<NB_A + NB_B + NB_C + NB_D + NB_E + ROWS, 256, 0, stream>>>(
      qkv_wb, qkvw, proj_wb, projw, exp_wb, expw, shr_wb, shrw, aout_bf,
      x, lng, lnb, bc, lnp_bf);
  // 2. qkv = ln1p @ qkv_w^T  — split-K=2 (grid-starved at z=1: 576 blocks)
  gemm_bf16<<<dim3(2304 / 128, ROWS / 128, 2), 256, 0, stream>>>(
      lnp_bf, KPA, qkv_wb, KPA, nullptr, 2304, KPA / 64, 7,
      nullptr, 0, nullptr, 0, 0, qkvp);
  // 3. rotary + per-head project (qkv 2-partial reduce fused) -> bf16
  rope_project<<<(ROWS * NH) / 4, 256, 0, stream>>>(qkvp, ac, qbb, kbb, vtb, q0b, k0b, v0b);
  // 4. split-S MFMA Lorentz flash attention (QBLK=128) -> bf16 partials
  attn_kernel<<<dim3(NSPLIT, T / 128, 48), 512, 0, stream>>>(
      qbb, kbb, vtb, q0b, k0b, v0b, ac, Opart, lpart, a0part);
  attn_combine<<<(48 * T) / 4, 256, 0, stream>>>(Opart, lpart, a0part, ac, aout_bf);
  // 5+6. attn proj split-K=2 (bf16 partials), fused reduce+LN+project
  gemm_bf16<<<dim3(768 / 128, ROWS / 128, 2), 256, 0, stream>>>(
      aout_bf, KPA, proj_wb, KPA, nullptr, NE, KPA / 64, 7,
      nullptr, 0, nullptr, 0, 0, ppartP);
  reduce_ln_project<<<ROWS, 256, 0, stream>>>(
      ppartP, 2, projb, x, x2, lng, lnb, bc, lnp_bf);
  // 7. mlp expand — split-K=2
  gemm_bf16<<<dim3(NEXP / 128, ROWS / 128, 2), 256, 0, stream>>>(
      lnp_bf, KPA, exp_wb, KPA, nullptr, NEXP, KPA / 64, 7,
      nullptr, 0, nullptr, 0, 0, hbbf);
  // 8. gelu + project (expand 2-partial reduce + bias fused, coalesced scalar)
  gelu_project<<<ROWS, 256, 0, stream>>>(hbbf, expb, mc, hp_bf);
  // 9+10. mlp shrink split-K=4 (bf16 partials), fused reduce+final project
  gemm_bf16<<<dim3(768 / 128, ROWS / 128, 4), 256, 0, stream>>>(
      hp_bf, KPB, shr_wb, KPB, nullptr, NE, KPB / 64, 13,
      nullptr, 0, nullptr, 0, 0, ppartS);
  reduce_final_project<<<ROWS, 256, 0, stream>>>(
      ppartS, 4, shrb, x2, bc, out);
}